// Round 1
// baseline (18.358 us; speedup 1.0000x reference)
//
#include <hip/hip_runtime.h>
#include <hip/hip_bf16.h>
#include <math.h>

#define EPS 1e-9f
// 4 / pi^2
#define FOUR_OVER_PI2 0.40528473456935108578f

__global__ __launch_bounds__(256) void ciou_loss_kernel(
    const float4* __restrict__ pb,
    const float4* __restrict__ tb,
    const int* __restrict__ mask,
    const float* __restrict__ box_norm,
    const float* __restrict__ cls_norm,
    float* __restrict__ out,
    int n)
{
    int i = blockIdx.x * blockDim.x + threadIdx.x;
    float local = 0.0f;
    if (i < n) {
        float4 a = pb[i];   // x1a, y1a, x2a, y2a
        float4 b = tb[i];   // x1b, y1b, x2b, y2b

        float x1a = a.x, y1a = a.y, x2a = a.z, y2a = a.w;
        float x1b = b.x, y1b = b.y, x2b = b.z, y2b = b.w;

        float xmin = fmaxf(x1a, x1b);
        float ymin = fmaxf(y1a, y1b);
        float xmax = fminf(x2a, x2b);
        float ymax = fminf(y2a, y2b);

        float iw = fmaxf(xmax - xmin, 0.0f);
        float ih = fmaxf(ymax - ymin, 0.0f);
        float inter = iw * ih;

        float wa = x2a - x1a, ha = y2a - y1a;
        float wb = x2b - x1b, hb = y2b - y1b;

        float area_a = wa * ha;
        float area_b = wb * hb;
        float uni = area_a + area_b - inter;
        float iou = inter / (uni + EPS);

        float cx = (x1a + x2a - x1b - x2b) * 0.5f;
        float cy = (y1a + y2a - y1b - y2b) * 0.5f;
        float cent2 = cx * cx + cy * cy;

        float cw = fmaxf(x2a, x2b) - fminf(x1a, x1b);
        float ch = fmaxf(y2a, y2b) - fminf(y1a, y1b);
        float diag2 = cw * cw + ch * ch;

        float diou = iou - cent2 / (diag2 + EPS);

        float at = atanf(wa / (ha + EPS)) - atanf(wb / (hb + EPS));
        float v = FOUR_OVER_PI2 * at * at;
        float alpha = v / (v - iou + 1.0f + EPS);
        float ciou = diou - alpha * v;

        float m = (mask[i] != 0) ? 1.0f : 0.0f;
        local = (1.0f - ciou) * m * box_norm[i];
    }

    // wave-level reduction (wave = 64 lanes on CDNA)
    #pragma unroll
    for (int off = 32; off > 0; off >>= 1)
        local += __shfl_down(local, off, 64);

    __shared__ float smem[4];
    int lane = threadIdx.x & 63;
    int wid  = threadIdx.x >> 6;
    if (lane == 0) smem[wid] = local;
    __syncthreads();

    if (threadIdx.x == 0) {
        float s = smem[0] + smem[1] + smem[2] + smem[3];
        atomicAdd(out, s / cls_norm[0]);
    }
}

extern "C" void kernel_launch(void* const* d_in, const int* in_sizes, int n_in,
                              void* d_out, int out_size, void* d_ws, size_t ws_size,
                              hipStream_t stream) {
    const float4* pb       = (const float4*)d_in[0];
    const float4* tb       = (const float4*)d_in[1];
    const int*    mask     = (const int*)d_in[2];
    const float*  box_norm = (const float*)d_in[3];
    const float*  cls_norm = (const float*)d_in[4];
    float* out = (float*)d_out;

    int n = in_sizes[3];  // box_norm has N elements

    // Harness poisons d_out once and never re-poisons between replays:
    // zero it every call so the atomic accumulation starts clean.
    hipMemsetAsync(out, 0, sizeof(float), stream);

    int block = 256;
    int grid = (n + block - 1) / block;
    ciou_loss_kernel<<<grid, block, 0, stream>>>(pb, tb, mask, box_norm, cls_norm, out, n);
}

// Round 2
// 10.862 us; speedup vs baseline: 1.6902x; 1.6902x over previous
//
#include <hip/hip_runtime.h>
#include <hip/hip_bf16.h>
#include <math.h>

#define EPS 1e-9f
// 4 / pi^2
#define FOUR_OVER_PI2 0.40528473456935108578f

#define BLOCK 256
#define ITER 4   // elements per thread in stage 1

__device__ __forceinline__ float ciou_loss_elem(float4 a, float4 b,
                                                int mval, float bn)
{
    float x1a = a.x, y1a = a.y, x2a = a.z, y2a = a.w;
    float x1b = b.x, y1b = b.y, x2b = b.z, y2b = b.w;

    float xmin = fmaxf(x1a, x1b);
    float ymin = fmaxf(y1a, y1b);
    float xmax = fminf(x2a, x2b);
    float ymax = fminf(y2a, y2b);

    float iw = fmaxf(xmax - xmin, 0.0f);
    float ih = fmaxf(ymax - ymin, 0.0f);
    float inter = iw * ih;

    float wa = x2a - x1a, ha = y2a - y1a;
    float wb = x2b - x1b, hb = y2b - y1b;

    float area_a = wa * ha;
    float area_b = wb * hb;
    float uni = area_a + area_b - inter;
    float iou = inter / (uni + EPS);

    float cx = (x1a + x2a - x1b - x2b) * 0.5f;
    float cy = (y1a + y2a - y1b - y2b) * 0.5f;
    float cent2 = cx * cx + cy * cy;

    float cw = fmaxf(x2a, x2b) - fminf(x1a, x1b);
    float ch = fmaxf(y2a, y2b) - fminf(y1a, y1b);
    float diag2 = cw * cw + ch * ch;

    float diou = iou - cent2 / (diag2 + EPS);

    float at = atanf(wa / (ha + EPS)) - atanf(wb / (hb + EPS));
    float v = FOUR_OVER_PI2 * at * at;
    float alpha = v / (v - iou + 1.0f + EPS);
    float ciou = diou - alpha * v;

    float m = (mval != 0) ? 1.0f : 0.0f;
    return (1.0f - ciou) * m * bn;
}

// Stage 1: per-block partial sums into d_ws (no atomics, no contention).
__global__ __launch_bounds__(BLOCK) void ciou_partial_kernel(
    const float4* __restrict__ pb,
    const float4* __restrict__ tb,
    const int* __restrict__ mask,
    const float* __restrict__ box_norm,
    float* __restrict__ partials,
    int n)
{
    int tid = blockIdx.x * BLOCK + threadIdx.x;
    int stride = gridDim.x * BLOCK;

    float local = 0.0f;
    #pragma unroll
    for (int it = 0; it < ITER; ++it) {
        int i = tid + it * stride;
        if (i < n) {
            local += ciou_loss_elem(pb[i], tb[i], mask[i], box_norm[i]);
        }
    }

    // wave-level reduction (wave = 64 lanes on CDNA)
    #pragma unroll
    for (int off = 32; off > 0; off >>= 1)
        local += __shfl_down(local, off, 64);

    __shared__ float smem[BLOCK / 64];
    int lane = threadIdx.x & 63;
    int wid  = threadIdx.x >> 6;
    if (lane == 0) smem[wid] = local;
    __syncthreads();

    if (threadIdx.x == 0) {
        float s = smem[0] + smem[1] + smem[2] + smem[3];
        partials[blockIdx.x] = s;   // plain store, one per block
    }
}

// Stage 2: one block reduces the partials and writes the final scalar.
__global__ __launch_bounds__(BLOCK) void ciou_final_kernel(
    const float* __restrict__ partials,
    const float* __restrict__ cls_norm,
    float* __restrict__ out,
    int nparts)
{
    float local = (threadIdx.x < nparts) ? partials[threadIdx.x] : 0.0f;

    #pragma unroll
    for (int off = 32; off > 0; off >>= 1)
        local += __shfl_down(local, off, 64);

    __shared__ float smem[BLOCK / 64];
    int lane = threadIdx.x & 63;
    int wid  = threadIdx.x >> 6;
    if (lane == 0) smem[wid] = local;
    __syncthreads();

    if (threadIdx.x == 0) {
        float s = smem[0] + smem[1] + smem[2] + smem[3];
        out[0] = s / cls_norm[0];   // plain store — no zeroing needed
    }
}

extern "C" void kernel_launch(void* const* d_in, const int* in_sizes, int n_in,
                              void* d_out, int out_size, void* d_ws, size_t ws_size,
                              hipStream_t stream) {
    const float4* pb       = (const float4*)d_in[0];
    const float4* tb       = (const float4*)d_in[1];
    const int*    mask     = (const int*)d_in[2];
    const float*  box_norm = (const float*)d_in[3];
    const float*  cls_norm = (const float*)d_in[4];
    float* out      = (float*)d_out;
    float* partials = (float*)d_ws;

    int n = in_sizes[3];  // box_norm has N elements

    int grid = (n + BLOCK * ITER - 1) / (BLOCK * ITER);   // 132 for N=134400

    ciou_partial_kernel<<<grid, BLOCK, 0, stream>>>(pb, tb, mask, box_norm, partials, n);
    ciou_final_kernel<<<1, BLOCK, 0, stream>>>(partials, cls_norm, out, grid);
}